// Round 1
// baseline (154.453 us; speedup 1.0000x reference)
//
#include <hip/hip_runtime.h>
#include <math.h>

#define NRR 512
#define NAA 512
#define NG  1024

// Host-side double-precision derived constants, rounded once to f32:
// BETA = 30deg, cb = cos, sb = sin
__device__ constexpr float CB = 0.86602540378443864676f;
__device__ constexpr float SB = 0.5f;
__device__ constexpr float RADAR_Y = -2886.7513459481288f; // -5000*tan(30deg)
__device__ constexpr float RADAR_Z = 5000.0f;
__device__ constexpr float RC_F = 5773.5026918962574f;     // 5000/cos(30deg)
__device__ constexpr float KLOG = 0.72134752044448170367f; // 0.5*log2(e)
__device__ constexpr float INV2PI = 0.15915494309189535f;

#if __has_builtin(__builtin_amdgcn_exp2f)
#define EXP2F(x) __builtin_amdgcn_exp2f(x)
#else
#define EXP2F(x) __expf((x) * 0.6931471805599453094f)
#endif

// Per-gaussian packed params: [rc, cc, A, B2] [D, w, 0, 0]
// value(r,c) = w * exp2(A*dr^2 + B2*dr*dc + D*dc^2)

__global__ void sar_precompute(const float* __restrict__ pos,
                               const float* __restrict__ cov,
                               const float* __restrict__ inten,
                               float* __restrict__ gp) {
    int n = blockIdx.x * blockDim.x + threadIdx.x;
    if (n >= NG) return;
    float qx = pos[n * 3 + 0];
    float qy = pos[n * 3 + 1] - RADAR_Y;
    float qz = pos[n * 3 + 2] - RADAR_Z;
    float Xr = qx;
    float Yr = -CB * qy - SB * qz;
    float Zr =  SB * qy - CB * qz;

    const float* C = cov + n * 9;
    float C00 = C[0], C01 = C[1], C02 = C[2];
    float C11 = C[4], C12 = C[5], C22 = C[8];
    // cov_r = R C R^T (rows r0=(1,0,0), r1=(0,-cb,-sb), r2=(0,sb,-cb))
    float c00p = C00;
    float c01p = -CB * C01 - SB * C02;
    float c02p =  SB * C01 - CB * C02;
    float c11p = CB * CB * C11 + 2.0f * CB * SB * C12 + SB * SB * C22;
    float c12p = CB * SB * (C22 - C11) + (CB * CB - SB * SB) * C12;
    float c22p = SB * SB * C11 - 2.0f * SB * CB * C12 + CB * CB * C22;

    float R2   = Yr * Yr + Zr * Zr + 1e-12f;
    float Rmin = sqrtf(R2);
    float rc = (Rmin + 256.0f) - RC_F;   // match reference op order
    float cc = Xr + 256.0f;

    // cov2 = J cov_r J^T + 1e-4 I ; J row0 = (0, Yr/Rmin, Zr/Rmin), row1 = (1,0,0)
    float a = (Yr * Yr * c11p + 2.0f * Yr * Zr * c12p + Zr * Zr * c22p) / R2 + 1e-4f;
    float b = (Yr * c01p + Zr * c02p) / Rmin;
    float d = c00p + 1e-4f;

    float det = a * d - b * b;
    float inv = 1.0f / det;
    float A  = -KLOG * d * inv;
    float B2 =  2.0f * KLOG * b * inv;
    float D  = -KLOG * a * inv;
    float w  = inten[n] * INV2PI * inv;

    float4* o = (float4*)(gp + (size_t)n * 8);
    o[0] = make_float4(rc, cc, A, B2);
    o[1] = make_float4(D, w, 0.0f, 0.0f);
}

// Block = 256 threads = 4 waves. Wave covers 64 consecutive cols, each thread
// 2 rows (amortizes dc-dependent terms). Tile = 64 cols x 8 rows.
__global__ __launch_bounds__(256) void sar_render(const float* __restrict__ gp,
                                                  float* __restrict__ out) {
    const int lane = threadIdx.x & 63;
    const int wid  = threadIdx.x >> 6;
    const int c    = blockIdx.x * 64 + lane;
    const int r0   = blockIdx.y * 8 + wid * 2;
    const float colf = (float)c;
    const float rf0  = (float)r0;
    const float rf1  = (float)(r0 + 1);
    float acc0 = 0.0f, acc1 = 0.0f;
    const float4* __restrict__ P = (const float4*)gp;
#pragma unroll 4
    for (int n = 0; n < NG; ++n) {
        float4 p0 = P[n * 2 + 0];
        float4 p1 = P[n * 2 + 1];
        float dc  = colf - p0.y;
        float u   = p0.w * dc;        // B2*dc
        float t   = p1.x * dc * dc;   // D*dc^2
        float dr0 = rf0 - p0.x;
        float dr1 = rf1 - p0.x;
        float m0 = fmaf(dr0, fmaf(p0.z, dr0, u), t);
        float m1 = fmaf(dr1, fmaf(p0.z, dr1, u), t);
        acc0 = fmaf(p1.y, EXP2F(m0), acc0);
        acc1 = fmaf(p1.y, EXP2F(m1), acc1);
    }
    out[(size_t)r0 * NAA + c]       = acc0;
    out[(size_t)(r0 + 1) * NAA + c] = acc1;
}

extern "C" void kernel_launch(void* const* d_in, const int* in_sizes, int n_in,
                              void* d_out, int out_size, void* d_ws, size_t ws_size,
                              hipStream_t stream) {
    const float* pos   = (const float*)d_in[0];
    const float* cov   = (const float*)d_in[1];
    const float* inten = (const float*)d_in[2];
    float* out = (float*)d_out;
    float* gp  = (float*)d_ws;  // 1024 * 8 floats = 32 KB

    sar_precompute<<<dim3(4), dim3(256), 0, stream>>>(pos, cov, inten, gp);
    sar_render<<<dim3(NAA / 64, NRR / 8), dim3(256), 0, stream>>>(gp, out);
}

// Round 2
// 71.162 us; speedup vs baseline: 2.1704x; 2.1704x over previous
//
#include <hip/hip_runtime.h>
#include <math.h>

#define NRR 512
#define NAA 512
#define NG  1024
#define TILE 16
#define TDIM 32            // 512/16
#define NT (TDIM*TDIM)     // 1024 tiles
#define CAP 1024           // max list entries per tile (== NG, cannot overflow)
#define MCUT 40.0f         // mahalanobis cutoff: exp(-20) ~ 2e-9

__device__ constexpr float CB = 0.86602540378443864676f;
__device__ constexpr float SB = 0.5f;
__device__ constexpr float RADAR_Y = -2886.7513459481288f; // -5000*tan(30deg)
__device__ constexpr float RADAR_Z = 5000.0f;
__device__ constexpr float RC_F = 5773.5026918962574f;     // 5000/cos(30deg)
__device__ constexpr float KLOG = 0.72134752044448170367f; // 0.5*log2(e)
__device__ constexpr float INV2PI = 0.15915494309189535f;

#if __has_builtin(__builtin_amdgcn_exp2f)
#define EXP2F(x) __builtin_amdgcn_exp2f(x)
#else
#define EXP2F(x) __expf((x) * 0.6931471805599453094f)
#endif

// Per-gaussian packed params: [rc, cc, A, B2] [D, w, 0, 0]
// value(r,c) = w * exp2(A*dr^2 + B2*dr*dc + D*dc^2)   (A,B2,D absorb -0.5*log2e)

__device__ __forceinline__ void precompute_one(
    const float* __restrict__ pos, const float* __restrict__ cov,
    const float* __restrict__ inten, int n,
    float& rc, float& cc, float& A, float& B2, float& D, float& w,
    float& a_out, float& d_out) {
    float qx = pos[n * 3 + 0];
    float qy = pos[n * 3 + 1] - RADAR_Y;
    float qz = pos[n * 3 + 2] - RADAR_Z;
    float Xr = qx;
    float Yr = -CB * qy - SB * qz;
    float Zr =  SB * qy - CB * qz;

    const float* C = cov + n * 9;
    float C00 = C[0], C01 = C[1], C02 = C[2];
    float C11 = C[4], C12 = C[5], C22 = C[8];
    float c00p = C00;
    float c01p = -CB * C01 - SB * C02;
    float c02p =  SB * C01 - CB * C02;
    float c11p = CB * CB * C11 + 2.0f * CB * SB * C12 + SB * SB * C22;
    float c12p = CB * SB * (C22 - C11) + (CB * CB - SB * SB) * C12;
    float c22p = SB * SB * C11 - 2.0f * SB * CB * C12 + CB * CB * C22;

    float R2   = Yr * Yr + Zr * Zr + 1e-12f;
    float Rmin = sqrtf(R2);
    rc = (Rmin + 256.0f) - RC_F;
    cc = Xr + 256.0f;

    float a = (Yr * Yr * c11p + 2.0f * Yr * Zr * c12p + Zr * Zr * c22p) / R2 + 1e-4f;
    float b = (Yr * c01p + Zr * c02p) / Rmin;
    float d = c00p + 1e-4f;

    float det = a * d - b * b;
    float inv = 1.0f / det;
    A  = -KLOG * d * inv;
    B2 =  2.0f * KLOG * b * inv;
    D  = -KLOG * a * inv;
    w  = inten[n] * INV2PI * inv;
    a_out = a; d_out = d;
}

// ---- Binned path ----------------------------------------------------------

__global__ void sar_bin(const float* __restrict__ pos,
                        const float* __restrict__ cov,
                        const float* __restrict__ inten,
                        float* __restrict__ gp,
                        unsigned int* __restrict__ cnt,
                        unsigned int* __restrict__ list) {
    int n = blockIdx.x * blockDim.x + threadIdx.x;
    if (n >= NG) return;
    float rc, cc, A, B2, D, w, a, d;
    precompute_one(pos, cov, inten, n, rc, cc, A, B2, D, w, a, d);

    float4* o = (float4*)(gp + (size_t)n * 8);
    o[0] = make_float4(rc, cc, A, B2);
    o[1] = make_float4(D, w, 0.0f, 0.0f);

    if (w < 1e-11f) return;           // contributes < 1e-11 anywhere
    float dR = sqrtf(MCUT * a);       // extent where mahal <= MCUT
    float dC = sqrtf(MCUT * d);
    int ty0 = max(0,        __float2int_rd((rc - dR) * (1.0f / TILE)));
    int ty1 = min(TDIM - 1, __float2int_rd((rc + dR) * (1.0f / TILE)));
    int tx0 = max(0,        __float2int_rd((cc - dC) * (1.0f / TILE)));
    int tx1 = min(TDIM - 1, __float2int_rd((cc + dC) * (1.0f / TILE)));
    for (int ty = ty0; ty <= ty1; ++ty)
        for (int tx = tx0; tx <= tx1; ++tx) {
            int t = ty * TDIM + tx;
            unsigned int idx = atomicAdd(&cnt[t], 1u);
            list[(size_t)t * CAP + idx] = (unsigned int)n;
        }
}

__global__ __launch_bounds__(256) void sar_splat(const float* __restrict__ gp,
                                                 const unsigned int* __restrict__ cnt,
                                                 const unsigned int* __restrict__ list,
                                                 float* __restrict__ out) {
    const int t  = blockIdx.x;
    const int tx = t & (TDIM - 1);
    const int ty = t >> 5;
    const int lc = threadIdx.x & (TILE - 1);
    const int lr = threadIdx.x >> 4;
    const int c = tx * TILE + lc;
    const int r = ty * TILE + lr;
    const float cf = (float)c;
    const float rf = (float)r;

    float acc = 0.0f;
    const int m = (int)cnt[t];
    const float4* __restrict__ P = (const float4*)gp;
    const unsigned int* __restrict__ L = list + (size_t)t * CAP;
#pragma unroll 2
    for (int i = 0; i < m; ++i) {
        unsigned int n = L[i];
        float4 p0 = P[2 * n];
        float4 p1 = P[2 * n + 1];
        float dr = rf - p0.x;
        float dc = cf - p0.y;
        float e = fmaf(dr, fmaf(p0.z, dr, p0.w * dc), p1.x * dc * dc);
        acc = fmaf(p1.y, EXP2F(e), acc);
    }
    out[(size_t)r * NAA + c] = acc;
}

// ---- Dense fallback (verified round-1 path) -------------------------------

__global__ void sar_precompute(const float* __restrict__ pos,
                               const float* __restrict__ cov,
                               const float* __restrict__ inten,
                               float* __restrict__ gp) {
    int n = blockIdx.x * blockDim.x + threadIdx.x;
    if (n >= NG) return;
    float rc, cc, A, B2, D, w, a, d;
    precompute_one(pos, cov, inten, n, rc, cc, A, B2, D, w, a, d);
    float4* o = (float4*)(gp + (size_t)n * 8);
    o[0] = make_float4(rc, cc, A, B2);
    o[1] = make_float4(D, w, 0.0f, 0.0f);
}

__global__ __launch_bounds__(256) void sar_render(const float* __restrict__ gp,
                                                  float* __restrict__ out) {
    const int lane = threadIdx.x & 63;
    const int wid  = threadIdx.x >> 6;
    const int c    = blockIdx.x * 64 + lane;
    const int r0   = blockIdx.y * 8 + wid * 2;
    const float colf = (float)c;
    const float rf0  = (float)r0;
    const float rf1  = (float)(r0 + 1);
    float acc0 = 0.0f, acc1 = 0.0f;
    const float4* __restrict__ P = (const float4*)gp;
#pragma unroll 4
    for (int n = 0; n < NG; ++n) {
        float4 p0 = P[n * 2 + 0];
        float4 p1 = P[n * 2 + 1];
        float dc  = colf - p0.y;
        float u   = p0.w * dc;
        float t   = p1.x * dc * dc;
        float dr0 = rf0 - p0.x;
        float dr1 = rf1 - p0.x;
        float m0 = fmaf(dr0, fmaf(p0.z, dr0, u), t);
        float m1 = fmaf(dr1, fmaf(p0.z, dr1, u), t);
        acc0 = fmaf(p1.y, EXP2F(m0), acc0);
        acc1 = fmaf(p1.y, EXP2F(m1), acc1);
    }
    out[(size_t)r0 * NAA + c]       = acc0;
    out[(size_t)(r0 + 1) * NAA + c] = acc1;
}

// ---- Launch ---------------------------------------------------------------

extern "C" void kernel_launch(void* const* d_in, const int* in_sizes, int n_in,
                              void* d_out, int out_size, void* d_ws, size_t ws_size,
                              hipStream_t stream) {
    const float* pos   = (const float*)d_in[0];
    const float* cov   = (const float*)d_in[1];
    const float* inten = (const float*)d_in[2];
    float* out = (float*)d_out;

    char* ws = (char*)d_ws;
    float*        gp   = (float*)ws;                      // 32 KB
    unsigned int* cnt  = (unsigned int*)(ws + 32768);     // 4 KB
    unsigned int* list = (unsigned int*)(ws + 40960);     // 4 MB
    const size_t needed = 40960 + (size_t)NT * CAP * 4;

    if (ws_size >= needed) {
        hipMemsetAsync(cnt, 0, NT * sizeof(unsigned int), stream);
        sar_bin<<<dim3((NG + 255) / 256), dim3(256), 0, stream>>>(pos, cov, inten, gp, cnt, list);
        sar_splat<<<dim3(NT), dim3(256), 0, stream>>>(gp, cnt, list, out);
    } else {
        sar_precompute<<<dim3((NG + 255) / 256), dim3(256), 0, stream>>>(pos, cov, inten, gp);
        sar_render<<<dim3(NAA / 64, NRR / 8), dim3(256), 0, stream>>>(gp, out);
    }
}

// Round 3
// 61.970 us; speedup vs baseline: 2.4924x; 1.1483x over previous
//
#include <hip/hip_runtime.h>
#include <math.h>

#define NRR 512
#define NAA 512
#define NG  1024
#define TILE 16
#define TDIM 32            // 512/16
#define NT (TDIM*TDIM)     // 1024 tiles
#define MCUT 40.0f         // mahalanobis cutoff: exp(-20) ~ 2e-9; culled mass
                           // bound: 1024 * 0.64 * e^-20 ~ 1.3e-6 << 3.9e-3 thr

__device__ constexpr float CB = 0.86602540378443864676f;
__device__ constexpr float SB = 0.5f;
__device__ constexpr float RADAR_Y = -2886.7513459481288f; // -5000*tan(30deg)
__device__ constexpr float RADAR_Z = 5000.0f;
__device__ constexpr float RC_F = 5773.5026918962574f;     // 5000/cos(30deg)
__device__ constexpr float KLOG = 0.72134752044448170367f; // 0.5*log2(e)
__device__ constexpr float INV2PI = 0.15915494309189535f;

#if __has_builtin(__builtin_amdgcn_exp2f)
#define EXP2F(x) __builtin_amdgcn_exp2f(x)
#else
#define EXP2F(x) __expf((x) * 0.6931471805599453094f)
#endif

// value(r,c) = w * exp2(A*dr^2 + B2*dr*dc + D*dc^2)  (A,B2,D absorb -0.5*log2e)
__device__ __forceinline__ void precompute_one(
    const float* __restrict__ pos, const float* __restrict__ cov,
    const float* __restrict__ inten, int n,
    float& rc, float& cc, float& A, float& B2, float& D, float& w,
    float& a_out, float& d_out) {
    float qx = pos[n * 3 + 0];
    float qy = pos[n * 3 + 1] - RADAR_Y;
    float qz = pos[n * 3 + 2] - RADAR_Z;
    float Xr = qx;
    float Yr = -CB * qy - SB * qz;
    float Zr =  SB * qy - CB * qz;

    const float* C = cov + n * 9;
    float C00 = C[0], C01 = C[1], C02 = C[2];
    float C11 = C[4], C12 = C[5], C22 = C[8];
    // cov_r = R C R^T (rows r0=(1,0,0), r1=(0,-cb,-sb), r2=(0,sb,-cb))
    float c00p = C00;
    float c01p = -CB * C01 - SB * C02;
    float c02p =  SB * C01 - CB * C02;
    float c11p = CB * CB * C11 + 2.0f * CB * SB * C12 + SB * SB * C22;
    float c12p = CB * SB * (C22 - C11) + (CB * CB - SB * SB) * C12;
    float c22p = SB * SB * C11 - 2.0f * SB * CB * C12 + CB * CB * C22;

    float R2   = Yr * Yr + Zr * Zr + 1e-12f;
    float Rmin = sqrtf(R2);
    rc = (Rmin + 256.0f) - RC_F;
    cc = Xr + 256.0f;

    // cov2 = J cov_r J^T + 1e-4 I ; J row0 = (0, Yr/Rmin, Zr/Rmin), row1=(1,0,0)
    float a = (Yr * Yr * c11p + 2.0f * Yr * Zr * c12p + Zr * Zr * c22p) / R2 + 1e-4f;
    float b = (Yr * c01p + Zr * c02p) / Rmin;
    float d = c00p + 1e-4f;

    float det = a * d - b * b;
    float inv = 1.0f / det;
    A  = -KLOG * d * inv;
    B2 =  2.0f * KLOG * b * inv;
    D  = -KLOG * a * inv;
    w  = inten[n] * INV2PI * inv;
    a_out = a; d_out = d;
}

// One block per 16x16 tile. Phase 1: 256 threads precompute 4 Gaussians each
// (replicated across blocks -- cheaper than a global round-trip + extra
// dispatch), cull against this tile's bbox, compact hits into LDS. Phase 2:
// one thread per pixel walks the LDS list (broadcast ds_read_b128).
__global__ __launch_bounds__(256) void sar_fused(const float* __restrict__ pos,
                                                 const float* __restrict__ cov,
                                                 const float* __restrict__ inten,
                                                 float* __restrict__ out) {
    __shared__ float4 s_p[2 * NG];   // 32 KB: {rc,cc,A,B2},{D,w,_,_} per hit
    __shared__ int    s_cnt;

    const int tx = blockIdx.x & (TDIM - 1);
    const int ty = blockIdx.x >> 5;
    const float c0 = (float)(tx * TILE);
    const float r0 = (float)(ty * TILE);

    if (threadIdx.x == 0) s_cnt = 0;
    __syncthreads();

#pragma unroll
    for (int k = 0; k < NG / 256; ++k) {
        int n = threadIdx.x + k * 256;
        float rc, cc, A, B2, D, w, a, d;
        precompute_one(pos, cov, inten, n, rc, cc, A, B2, D, w, a, d);
        float dR = sqrtf(MCUT * a);      // marginal extent where mahal <= MCUT
        float dC = sqrtf(MCUT * d);
        bool hit = (w >= 1e-11f) &
                   (rc + dR >= r0) & (rc - dR <= r0 + (TILE - 1)) &
                   (cc + dC >= c0) & (cc - dC <= c0 + (TILE - 1));
        if (hit) {
            int i = atomicAdd(&s_cnt, 1);
            s_p[2 * i]     = make_float4(rc, cc, A, B2);
            s_p[2 * i + 1] = make_float4(D, w, 0.0f, 0.0f);
        }
    }
    __syncthreads();

    const int m  = s_cnt;
    const int lc = threadIdx.x & (TILE - 1);
    const int lr = threadIdx.x >> 4;
    const float cf = c0 + (float)lc;
    const float rf = r0 + (float)lr;

    float acc = 0.0f;
#pragma unroll 2
    for (int i = 0; i < m; ++i) {
        float4 p0 = s_p[2 * i];
        float4 p1 = s_p[2 * i + 1];
        float dr = rf - p0.x;
        float dc = cf - p0.y;
        float e = fmaf(dr, fmaf(p0.z, dr, p0.w * dc), p1.x * dc * dc);
        acc = fmaf(p1.y, EXP2F(e), acc);
    }
    out[(size_t)(ty * TILE + lr) * NAA + (tx * TILE + lc)] = acc;
}

extern "C" void kernel_launch(void* const* d_in, const int* in_sizes, int n_in,
                              void* d_out, int out_size, void* d_ws, size_t ws_size,
                              hipStream_t stream) {
    const float* pos   = (const float*)d_in[0];
    const float* cov   = (const float*)d_in[1];
    const float* inten = (const float*)d_in[2];
    float* out = (float*)d_out;
    (void)d_ws; (void)ws_size;

    sar_fused<<<dim3(NT), dim3(256), 0, stream>>>(pos, cov, inten, out);
}

// Round 4
// 61.961 us; speedup vs baseline: 2.4927x; 1.0001x over previous
//
#include <hip/hip_runtime.h>
#include <math.h>

#define NRR 512
#define NAA 512
#define NG  1024
#define TILE 16
#define TDIM 32            // 512/16
#define NT (TDIM*TDIM)     // 1024 tiles
#define MCUT 40.0f         // mahal cutoff: culled mass <= 1024*0.64*e^-20 ~ 1.3e-6
                           // << 3.9e-3 threshold (det >= 0.25 since cov2 >= 0.5I proj)

__device__ constexpr float CB = 0.86602540378443864676f;
__device__ constexpr float SB = 0.5f;
__device__ constexpr float RADAR_Y = -2886.7513459481288f; // -5000*tan(30deg)
__device__ constexpr float RADAR_Z = 5000.0f;
__device__ constexpr float RC_F = 5773.5026918962574f;     // 5000/cos(30deg)
__device__ constexpr float KLOG = 0.72134752044448170367f; // 0.5*log2(e)
__device__ constexpr float INV2PI = 0.15915494309189535f;

#if __has_builtin(__builtin_amdgcn_exp2f)
#define EXP2F(x) __builtin_amdgcn_exp2f(x)
#else
#define EXP2F(x) __expf((x) * 0.6931471805599453094f)
#endif

// value(r,c) = w * exp2(A*dr^2 + B2*dr*dc + D*dc^2)  (A,B2,D absorb -0.5*log2e)
__device__ __forceinline__ void precompute_one(
    const float* __restrict__ pos, const float* __restrict__ cov,
    const float* __restrict__ inten, int n,
    float& rc, float& cc, float& A, float& B2, float& D, float& w,
    float& a_out, float& d_out) {
    float qx = pos[n * 3 + 0];
    float qy = pos[n * 3 + 1] - RADAR_Y;
    float qz = pos[n * 3 + 2] - RADAR_Z;
    float Xr = qx;
    float Yr = -CB * qy - SB * qz;
    float Zr =  SB * qy - CB * qz;

    const float* C = cov + n * 9;
    float C00 = C[0], C01 = C[1], C02 = C[2];
    float C11 = C[4], C12 = C[5], C22 = C[8];
    // cov_r = R C R^T (rows r0=(1,0,0), r1=(0,-cb,-sb), r2=(0,sb,-cb))
    float c00p = C00;
    float c01p = -CB * C01 - SB * C02;
    float c02p =  SB * C01 - CB * C02;
    float c11p = CB * CB * C11 + 2.0f * CB * SB * C12 + SB * SB * C22;
    float c12p = CB * SB * (C22 - C11) + (CB * CB - SB * SB) * C12;
    float c22p = SB * SB * C11 - 2.0f * SB * CB * C12 + CB * CB * C22;

    float R2   = Yr * Yr + Zr * Zr + 1e-12f;
    float Rmin = sqrtf(R2);
    rc = (Rmin + 256.0f) - RC_F;
    cc = Xr + 256.0f;

    // cov2 = J cov_r J^T + 1e-4 I ; J row0=(0,Yr/Rmin,Zr/Rmin), row1=(1,0,0)
    float a = (Yr * Yr * c11p + 2.0f * Yr * Zr * c12p + Zr * Zr * c22p) / R2 + 1e-4f;
    float b = (Yr * c01p + Zr * c02p) / Rmin;
    float d = c00p + 1e-4f;

    float det = a * d - b * b;
    float inv = 1.0f / det;
    A  = -KLOG * d * inv;
    B2 =  2.0f * KLOG * b * inv;
    D  = -KLOG * a * inv;
    w  = inten[n] * INV2PI * inv;
    a_out = a; d_out = d;
}

// Kernel 1: runs the scattered-load heavy math ONCE (208 scattered VMEM
// instrs total vs 213K when replicated per tile-block in R3).
// cull[n] = {rc, cc, dR, dC}   (dense 16 KB, phase-1 streaming)
// par [n] = {A, B2, D, w}      (loaded only on bbox hit)
__global__ void sar_precompute(const float* __restrict__ pos,
                               const float* __restrict__ cov,
                               const float* __restrict__ inten,
                               float4* __restrict__ cull,
                               float4* __restrict__ par) {
    int n = blockIdx.x * blockDim.x + threadIdx.x;
    if (n >= NG) return;
    float rc, cc, A, B2, D, w, a, d;
    precompute_one(pos, cov, inten, n, rc, cc, A, B2, D, w, a, d);
    float dR = sqrtf(MCUT * a);      // marginal extent where mahal <= MCUT
    float dC = sqrtf(MCUT * d);
    if (w < 1e-11f) { dR = -1.0f; dC = -1.0f; }   // never hits any tile
    cull[n] = make_float4(rc, cc, dR, dC);
    par[n]  = make_float4(A, B2, D, w);
}

// Kernel 2: one block per 16x16 tile. Phase 1: dense float4 stream over the
// cull array (L2-broadcast), bbox test, hits pushed to LDS. Phase 2: one
// thread per pixel walks the LDS list.
__global__ __launch_bounds__(256) void sar_splat(const float4* __restrict__ cull,
                                                 const float4* __restrict__ par,
                                                 float* __restrict__ out) {
    __shared__ float4 s_p[2 * NG];   // 32 KB cap=NG: overflow impossible
    __shared__ int    s_cnt;

    const int tx = blockIdx.x & (TDIM - 1);
    const int ty = blockIdx.x >> 5;
    const float c0 = (float)(tx * TILE);
    const float r0 = (float)(ty * TILE);

    if (threadIdx.x == 0) s_cnt = 0;
    __syncthreads();

#pragma unroll
    for (int k = 0; k < NG / 256; ++k) {
        int n = threadIdx.x + k * 256;
        float4 q = cull[n];
        bool hit = (q.x + q.z >= r0) & (q.x - q.z <= r0 + (TILE - 1)) &
                   (q.y + q.w >= c0) & (q.y - q.w <= c0 + (TILE - 1));
        if (hit) {
            float4 p = par[n];
            int i = atomicAdd(&s_cnt, 1);
            s_p[2 * i]     = make_float4(q.x, q.y, p.x, p.y); // rc,cc,A,B2
            s_p[2 * i + 1] = make_float4(p.z, p.w, 0.0f, 0.0f); // D,w
        }
    }
    __syncthreads();

    const int m  = s_cnt;
    const int lc = threadIdx.x & (TILE - 1);
    const int lr = threadIdx.x >> 4;
    const float cf = c0 + (float)lc;
    const float rf = r0 + (float)lr;

    float acc = 0.0f;
#pragma unroll 2
    for (int i = 0; i < m; ++i) {
        float4 p0 = s_p[2 * i];
        float4 p1 = s_p[2 * i + 1];
        float dr = rf - p0.x;
        float dc = cf - p0.y;
        float e = fmaf(dr, fmaf(p0.z, dr, p0.w * dc), p1.x * dc * dc);
        acc = fmaf(p1.y, EXP2F(e), acc);
    }
    out[(size_t)(ty * TILE + lr) * NAA + (tx * TILE + lc)] = acc;
}

// Fallback (R3 verified single-kernel path) if ws is unusable.
__global__ __launch_bounds__(256) void sar_fused(const float* __restrict__ pos,
                                                 const float* __restrict__ cov,
                                                 const float* __restrict__ inten,
                                                 float* __restrict__ out) {
    __shared__ float4 s_p[2 * NG];
    __shared__ int    s_cnt;
    const int tx = blockIdx.x & (TDIM - 1);
    const int ty = blockIdx.x >> 5;
    const float c0 = (float)(tx * TILE);
    const float r0 = (float)(ty * TILE);
    if (threadIdx.x == 0) s_cnt = 0;
    __syncthreads();
#pragma unroll
    for (int k = 0; k < NG / 256; ++k) {
        int n = threadIdx.x + k * 256;
        float rc, cc, A, B2, D, w, a, d;
        precompute_one(pos, cov, inten, n, rc, cc, A, B2, D, w, a, d);
        float dR = sqrtf(MCUT * a);
        float dC = sqrtf(MCUT * d);
        bool hit = (w >= 1e-11f) &
                   (rc + dR >= r0) & (rc - dR <= r0 + (TILE - 1)) &
                   (cc + dC >= c0) & (cc - dC <= c0 + (TILE - 1));
        if (hit) {
            int i = atomicAdd(&s_cnt, 1);
            s_p[2 * i]     = make_float4(rc, cc, A, B2);
            s_p[2 * i + 1] = make_float4(D, w, 0.0f, 0.0f);
        }
    }
    __syncthreads();
    const int m  = s_cnt;
    const int lc = threadIdx.x & (TILE - 1);
    const int lr = threadIdx.x >> 4;
    const float cf = c0 + (float)lc;
    const float rf = r0 + (float)lr;
    float acc = 0.0f;
#pragma unroll 2
    for (int i = 0; i < m; ++i) {
        float4 p0 = s_p[2 * i];
        float4 p1 = s_p[2 * i + 1];
        float dr = rf - p0.x;
        float dc = cf - p0.y;
        float e = fmaf(dr, fmaf(p0.z, dr, p0.w * dc), p1.x * dc * dc);
        acc = fmaf(p1.y, EXP2F(e), acc);
    }
    out[(size_t)(ty * TILE + lr) * NAA + (tx * TILE + lc)] = acc;
}

extern "C" void kernel_launch(void* const* d_in, const int* in_sizes, int n_in,
                              void* d_out, int out_size, void* d_ws, size_t ws_size,
                              hipStream_t stream) {
    const float* pos   = (const float*)d_in[0];
    const float* cov   = (const float*)d_in[1];
    const float* inten = (const float*)d_in[2];
    float* out = (float*)d_out;

    if (ws_size >= 2 * NG * sizeof(float4)) {
        float4* cull = (float4*)d_ws;          // 16 KB
        float4* par  = cull + NG;              // 16 KB
        sar_precompute<<<dim3((NG + 255) / 256), dim3(256), 0, stream>>>(
            pos, cov, inten, cull, par);
        sar_splat<<<dim3(NT), dim3(256), 0, stream>>>(cull, par, out);
    } else {
        sar_fused<<<dim3(NT), dim3(256), 0, stream>>>(pos, cov, inten, out);
    }
}